// Round 16
// baseline (135.740 us; speedup 1.0000x reference)
//
#include <hip/hip_runtime.h>
#include <cstddef>

#define NB 65536
#define SL 5

typedef _Float16 f16;
typedef f16 half8 __attribute__((ext_vector_type(8)));
typedef float f32x4 __attribute__((ext_vector_type(4)));

// Fast 1-ulp reciprocal (v_rcp_f32) instead of IEEE divide microcode.
__device__ __forceinline__ float sigm(float x) {
  return __builtin_amdgcn_rcpf(1.0f + __expf(-x));
}
__device__ __forceinline__ float tanh_f(float x) {
  return __builtin_fmaf(2.0f, __builtin_amdgcn_rcpf(1.0f + __expf(-2.0f * x)), -1.0f);
}
__device__ __forceinline__ unsigned int pkh2(float a, float b) {
  return (unsigned int)__builtin_bit_cast(unsigned short, (_Float16)a)
       | ((unsigned int)__builtin_bit_cast(unsigned short, (_Float16)b) << 16);
}
__device__ __forceinline__ unsigned int pku2(unsigned short a, unsigned short b) {
  return (unsigned int)a | ((unsigned int)b << 16);
}
__device__ __forceinline__ float loh(unsigned int u) {
  return (float)__builtin_bit_cast(_Float16, (unsigned short)(u & 0xffffu));
}
__device__ __forceinline__ float hih(unsigned int u) {
  return (float)__builtin_bit_cast(_Float16, (unsigned short)(u >> 16));
}

// ---------------------------------------------------------------------------
// prep: f16 MFMA A-fragments (unchanged).
// ---------------------------------------------------------------------------
__global__ __launch_bounds__(256) void prep_kernel(
    const float* __restrict__ wi_fw, const float* __restrict__ wh_fw,
    const float* __restrict__ bi_fw, const float* __restrict__ bh_fw,
    const float* __restrict__ wi_bw, const float* __restrict__ wh_bw,
    const float* __restrict__ bi_bw, const float* __restrict__ bh_bw,
    const float* __restrict__ msg_w, const float* __restrict__ msg_b,
    const float* __restrict__ gw_ih, const float* __restrict__ gw_hh,
    const float* __restrict__ gb_ih, const float* __restrict__ gb_hh,
    unsigned short* __restrict__ wfrag, float* __restrict__ bsum,
    unsigned short* __restrict__ mfrag, float* __restrict__ mbias)
{
  const int t = blockIdx.x * 256 + threadIdx.x;
  if (t < 36864) {
    const int i = t & 7, lane = (t >> 3) & 63, fid = t >> 9;
    const int kc = fid % 3, mt = (fid / 3) % 3, ug = (fid / 9) & 3, dir = fid / 36;
    const int k = kc * 32 + (lane >> 4) * 8 + i;
    const int r16 = lane & 15;
    const int j = ug * 12 + mt * 4 + (r16 >> 2);
    const int g = r16 & 3;
    const float* wi = dir ? wi_bw : wi_fw;
    const float* wh = dir ? wh_bw : wh_fw;
    const float v = (k < 48) ? wi[(g * 48 + j) * 48 + k] : wh[(g * 48 + j) * 48 + (k - 48)];
    wfrag[t] = __builtin_bit_cast(unsigned short, (_Float16)v);
  } else if (t < 37248) {
    const int q = t - 36864;
    const int r16 = q & 15, mt = (q >> 4) % 3, ug = (q / 48) & 3, dir = q / 192;
    const int j = ug * 12 + mt * 4 + (r16 >> 2);
    const int g = r16 & 3;
    const int row = g * 48 + j;
    bsum[q] = dir ? (bi_bw[row] + bh_bw[row]) : (bi_fw[row] + bh_fw[row]);
  } else if (t < 39296) {
    const int q = t - 37248;
    const int i = q & 7, lane = (q >> 3) & 63, fid = q >> 9;
    const int k = ((lane >> 4) << 3) + i;
    const int r16 = lane & 15;
    float v = 0.0f;
    if (fid == 0) {
      if (r16 < 12 && k >= 12 && k < 24) v = msg_w[r16 * 12 + (k - 12)];
    } else {
      const int R = (fid - 1) * 16 + r16;
      const int kind = R / 12, j = R % 12;
      if (kind == 0)      v = (k < 12) ? gw_ih[j * 12 + k]          : ((k < 24) ? gw_hh[j * 12 + (k - 12)] : 0.0f);
      else if (kind == 1) v = (k < 12) ? gw_ih[(12 + j) * 12 + k]   : ((k < 24) ? gw_hh[(12 + j) * 12 + (k - 12)] : 0.0f);
      else if (kind == 2) v = (k < 12) ? gw_ih[(24 + j) * 12 + k]   : 0.0f;
      else                v = (k >= 12 && k < 24) ? gw_hh[(24 + j) * 12 + (k - 12)] : 0.0f;
    }
    mfrag[q] = __builtin_bit_cast(unsigned short, (_Float16)v);
  } else if (t < 39360) {
    const int q = t - 39296;
    if (q < 16) mbias[q] = (q < 12) ? msg_b[q] : 0.0f;
    else {
      const int R = q - 16, kind = R / 12, j = R % 12;
      float v;
      if (kind == 0)      v = gb_ih[j] + gb_hh[j];
      else if (kind == 1) v = gb_ih[12 + j] + gb_hh[12 + j];
      else if (kind == 2) v = gb_ih[24 + j];
      else                v = gb_hh[24 + j];
      mbias[q] = v;
    }
  }
}

// ---------------------------------------------------------------------------
// Phase A via MFMA (unchanged from round 13).
// ---------------------------------------------------------------------------
__global__ __launch_bounds__(256) void msg_mfma_kernel(
    const float* __restrict__ nf, const float* __restrict__ pos,
    const float* __restrict__ att,
    const unsigned short* __restrict__ mfrag, const float* __restrict__ mbias,
    unsigned short* __restrict__ xth)
{
  __shared__ unsigned short B_lds[256][40];   // f16 bits, 80B rows
  __shared__ unsigned short g_lds[256][50];   // f16 bits, 100B rows
  unsigned short* xbuf = &g_lds[0][0];        // [64][50] alias (final pass only)

  const int tid  = threadIdx.x;
  const int lane = tid & 63;
  const int w    = __builtin_amdgcn_readfirstlane(tid >> 6);
  const int c16  = lane & 15;
  const int grp  = lane >> 4;
  const int own  = tid;
  const int node = own & 3;
  const int sl   = (own >> 6) * 16 + ((own >> 4) & 3) * 4 + ((own >> 2) & 3);

  half8 A1 = *reinterpret_cast<const half8*>(mfrag + (size_t)lane * 8);
  half8 A2[3];
#pragma unroll
  for (int mt = 0; mt < 3; ++mt)
    A2[mt] = *reinterpret_cast<const half8*>(mfrag + (size_t)((1 + mt) * 64 + lane) * 8);
  const f32x4 bias1 = *reinterpret_cast<const f32x4*>(mbias + grp * 4);
  f32x4 bias2[3];
#pragma unroll
  for (int mt = 0; mt < 3; ++mt)
    bias2[mt] = *reinterpret_cast<const f32x4*>(mbias + 16 + mt * 16 + grp * 4);

  {
    unsigned int* bz = reinterpret_cast<unsigned int*>(&B_lds[0][0]);
#pragma unroll
    for (int q = 0; q < 6; ++q)  bz[tid * 20 + q] = 0u;
#pragma unroll
    for (int q = 12; q < 16; ++q) bz[tid * 20 + q] = 0u;
  }

  const int sid = blockIdx.x * 64 + sl;
  const int s   = sid >> 16;
  const int b   = sid & (NB - 1);
  float h[12];
  {
    const size_t ib = ((size_t)(b * SL + s) * 4 + node) * 6;
    const float2* n2 = (const float2*)(nf  + ib);
    const float2* p2 = (const float2*)(pos + ib);
#pragma unroll
    for (int q = 0; q < 3; q++) {
      float2 v = n2[q]; h[q*2]   = v.x; h[q*2+1]   = v.y;
      float2 u = p2[q]; h[6+q*2] = u.x; h[6+q*2+1] = u.y;
    }
  }
  float ta[4];
  {
    float4 v = *(const float4*)(att + ((size_t)(b * SL + s) * 4 + node) * 4);
    ta[0] = v.x; ta[1] = v.y; ta[2] = v.z; ta[3] = v.w;
  }
  {
    unsigned int* bp = (unsigned int*)&B_lds[own][0];
#pragma unroll
    for (int d = 0; d < 6; ++d) bp[6 + d] = pkh2(h[2*d], h[2*d+1]);
  }
  __syncthreads();

#pragma unroll 1
  for (int pass = 0; pass < 2; ++pass) {
    // --- GEMM1: m_all (rows 0..11) ---
#pragma unroll
    for (int nt = 0; nt < 4; ++nt) {
      const int col = w * 64 + nt * 16 + c16;
      half8 B = *reinterpret_cast<const half8*>(&B_lds[col][grp * 8]);
      f32x4 C = __builtin_amdgcn_mfma_f32_16x16x32_f16(A1, B, bias1, 0, 0, 0);
      if (grp < 3) {
        unsigned int* gp = (unsigned int*)&g_lds[col][0];
        gp[grp * 2]     = pkh2(C[0], C[1]);
        gp[grp * 2 + 1] = pkh2(C[2], C[3]);
      }
    }
    __syncthreads();

    // --- attention mix (paired u32 reads; quad-broadcast) ---
    {
      const int cb = own & ~3;
      float mv[12];
#pragma unroll
      for (int d = 0; d < 12; ++d) mv[d] = 0.0f;
#pragma unroll
      for (int ww = 0; ww < 4; ++ww) {
        const float a = ta[ww];
        const unsigned int* gp = (const unsigned int*)&g_lds[cb + ww][0];
#pragma unroll
        for (int dq = 0; dq < 6; ++dq) {
          const unsigned int u = gp[dq];
          mv[2*dq]   = __builtin_fmaf(a, loh(u), mv[2*dq]);
          mv[2*dq+1] = __builtin_fmaf(a, hih(u), mv[2*dq+1]);
        }
      }
      unsigned int* bp = (unsigned int*)&B_lds[own][0];
#pragma unroll
      for (int d = 0; d < 6; ++d) bp[d] = pkh2(mv[2*d], mv[2*d+1]);
    }
    __syncthreads();

    // --- GEMM2: gates, 48 rows = [r | z | n_ih | n_hh] ---
#pragma unroll
    for (int nt = 0; nt < 4; ++nt) {
      const int col = w * 64 + nt * 16 + c16;
      half8 B = *reinterpret_cast<const half8*>(&B_lds[col][grp * 8]);
      f32x4 C0 = __builtin_amdgcn_mfma_f32_16x16x32_f16(A2[0], B, bias2[0], 0, 0, 0);
      f32x4 C1 = __builtin_amdgcn_mfma_f32_16x16x32_f16(A2[1], B, bias2[1], 0, 0, 0);
      f32x4 C2 = __builtin_amdgcn_mfma_f32_16x16x32_f16(A2[2], B, bias2[2], 0, 0, 0);
      unsigned int* gp = (unsigned int*)&g_lds[col][0];
      gp[grp * 2]      = pkh2(C0[0], C0[1]);
      gp[grp * 2 + 1]  = pkh2(C0[2], C0[3]);
      gp[8 + grp * 2]     = pkh2(C1[0], C1[1]);
      gp[8 + grp * 2 + 1] = pkh2(C1[2], C1[3]);
      gp[16 + grp * 2]     = pkh2(C2[0], C2[1]);
      gp[16 + grp * 2 + 1] = pkh2(C2[2], C2[3]);
    }
    __syncthreads();

    // --- GRU update (gate reads hoisted; pass 1 writes to xbuf) ---
    {
      unsigned int ur[6], uz[6], ui[6], uh[6];
      const unsigned int* gq = (const unsigned int*)&g_lds[own][0];
#pragma unroll
      for (int jq = 0; jq < 6; ++jq) {
        ur[jq] = gq[jq];
        uz[jq] = gq[6 + jq];
        ui[jq] = gq[12 + jq];
        uh[jq] = gq[18 + jq];
      }
      if (pass) __syncthreads();   // xbuf aliases g_lds: all gate reads done
#pragma unroll
      for (int jq = 0; jq < 6; ++jq) {
        {
          const float r = sigm(loh(ur[jq])), z = sigm(loh(uz[jq]));
          const float g = tanh_f(loh(ui[jq]) + r * loh(uh[jq]));
          h[2*jq] = (1.0f - z) * g + z * h[2*jq];
        }
        {
          const float r = sigm(hih(ur[jq])), z = sigm(hih(uz[jq]));
          const float g = tanh_f(hih(ui[jq]) + r * hih(uh[jq]));
          h[2*jq+1] = (1.0f - z) * g + z * h[2*jq+1];
        }
      }
      if (pass == 0) {
        unsigned int* bp = (unsigned int*)&B_lds[own][0];
#pragma unroll
        for (int d = 0; d < 6; ++d) bp[6 + d] = pkh2(h[2*d], h[2*d+1]);
      } else {
#pragma unroll
        for (int d = 0; d < 12; ++d)
          xbuf[sl * 50 + d * 4 + node] =
              __builtin_bit_cast(unsigned short, (_Float16)h[d]);
      }
    }
    __syncthreads();
  }

  // --- store: lane i = batch b0+i reads xbuf[i*50+f] (conflict-free) ---
  const int b0   = (blockIdx.x * 64) & (NB - 1);
  const int sblk = blockIdx.x >> 10;           // block-uniform s
#pragma unroll
  for (int ff = 0; ff < 12; ++ff) {
    const int f = w * 12 + ff;
    xth[(size_t)(sblk * 48 + f) * NB + b0 + lane] = xbuf[lane * 50 + f];
  }
}

// ---------------------------------------------------------------------------
// Phase B+C: biLSTM via MFMA + MLP head.
// r15 structure (1 barrier/step, full x prefetch, double-buffered hb) with
// the xs-fill bug FIXED: xs rows hold only k=0..31 (all B0 needs; k=32..47
// lives in hb's straddle slice). Each wave fills 4 halfs (f = w*4+ff) ->
// 2 u32 at offset w*2 in a 21-u32 row — disjoint and in-bounds (r15 wrote
// 24 u32 into 20-u32 rows -> row overlap -> absmax 4.4e-2). Rows padded to
// 42 halfs (21 dwords, odd) -> prologue writes & B0 reads bank-spread.
// LDS 63744B (2 blocks/CU). Numerics identical to r14.
// ---------------------------------------------------------------------------
__global__ __launch_bounds__(512) void lstm_mfma_kernel(
    const unsigned short* __restrict__ xth,
    const unsigned short* __restrict__ wfrag,
    const float* __restrict__ bsum,
    const float* __restrict__ e1w, const float* __restrict__ e1b,
    const float* __restrict__ e2w, const float* __restrict__ e2b,
    const float* __restrict__ e3w, const float* __restrict__ e3b,
    float* __restrict__ out)
{
  __shared__ __align__(16) unsigned char poolc[63744];
  unsigned short* hb  = (unsigned short*)poolc;            // [2][2][64][72] halfs, 36864B
  unsigned short* xs  = (unsigned short*)(poolc + 36864);  // [5][64][42] halfs, 26880B
  float*          hf  = (float*)(poolc + 36864);           // [64][100] f32 (aliases xs)
  unsigned short* e1o = (unsigned short*)poolc;            // [64][54] f16 (aliases hb)
  float*          e2o = (float*)(poolc + 36864);           // [64][44] f32 (aliases hf)

  const int tid  = threadIdx.x;
  const int lane = tid & 63;
  const int w    = __builtin_amdgcn_readfirstlane(tid >> 6);
  const int dir  = w & 1;
  const int ug   = w >> 1;
  const int b0   = blockIdx.x * 64;
  const int col  = lane & 15;
  const int grp  = lane >> 4;

  half8 A[3][3];
#pragma unroll
  for (int mt = 0; mt < 3; ++mt)
#pragma unroll
    for (int kc = 0; kc < 3; ++kc) {
      const int fid = ((dir * 4 + ug) * 3 + mt) * 3 + kc;
      A[mt][kc] = *reinterpret_cast<const half8*>(wfrag + (size_t)(fid * 64 + lane) * 8);
    }
  unsigned int bp[3][2];
#pragma unroll
  for (int mt = 0; mt < 3; ++mt) {
    const f32x4 bf = *reinterpret_cast<const f32x4*>(bsum + ((dir * 4 + ug) * 3 + mt) * 16 + grp * 4);
    bp[mt][0] = pkh2(bf[0], bf[1]);
    bp[mt][1] = pkh2(bf[2], bf[3]);
  }

  // ---- prologue: xs fill (k=0..31 only, 4 halfs/wave/step), hb[0] h-zero,
  //      hb[0] x[32..47] copy. Disjoint destinations -> single barrier.
  {
#pragma unroll
    for (int s = 0; s < 5; ++s) {
      unsigned short xa[4];
#pragma unroll
      for (int ff = 0; ff < 4; ++ff)
        xa[ff] = xth[(size_t)(s * 48 + w * 4 + ff) * NB + b0 + lane];
      unsigned int* xp = (unsigned int*)xs + (s * 64 + lane) * 21 + w * 2;
      xp[0] = pku2(xa[0], xa[1]);
      xp[1] = pku2(xa[2], xa[3]);
    }
    unsigned int* hz = (unsigned int*)hb + (dir * 64 + lane) * 36 + 8 + ug * 6;
#pragma unroll
    for (int jj = 0; jj < 6; ++jj) hz[jj] = 0u;
    const int sp = dir ? 4 : 0;
    unsigned short xv[4];
#pragma unroll
    for (int i = 0; i < 4; ++i)
      xv[i] = xth[(size_t)(sp * 48 + 32 + ug * 4 + i) * NB + b0 + lane];
    unsigned int* xc = (unsigned int*)hb + (dir * 64 + lane) * 36 + ug * 2;
    xc[0] = pku2(xv[0], xv[1]);
    xc[1] = pku2(xv[2], xv[3]);
  }
  __syncthreads();

  float c[3][4];
#pragma unroll
  for (int mt = 0; mt < 3; ++mt)
#pragma unroll
    for (int nt = 0; nt < 4; ++nt) c[mt][nt] = 0.0f;

#pragma unroll 1
  for (int st = 0; st < 5; ++st) {
    const int p  = st & 1;
    const int s0 = dir ? (4 - st) : st;
    const unsigned short* xrow = xs + (s0 * 64) * 42;
    const unsigned short* hrow = hb + ((p * 2 + dir) * 64) * 72;
    unsigned int hp[3][2];
#pragma unroll
    for (int nt = 0; nt < 4; ++nt) {
      const int n = nt * 16 + col;
      half8 B0 = *reinterpret_cast<const half8*>(xrow + n * 42 + grp * 8);
      half8 B1 = *reinterpret_cast<const half8*>(hrow + n * 72 + grp * 8);
      half8 B2 = *reinterpret_cast<const half8*>(hrow + n * 72 + 32 + grp * 8);
      f32x4 C0, C1, C2;
      C0[0] = loh(bp[0][0]); C0[1] = hih(bp[0][0]); C0[2] = loh(bp[0][1]); C0[3] = hih(bp[0][1]);
      C1[0] = loh(bp[1][0]); C1[1] = hih(bp[1][0]); C1[2] = loh(bp[1][1]); C1[3] = hih(bp[1][1]);
      C2[0] = loh(bp[2][0]); C2[1] = hih(bp[2][0]); C2[2] = loh(bp[2][1]); C2[3] = hih(bp[2][1]);
      C0 = __builtin_amdgcn_mfma_f32_16x16x32_f16(A[0][0], B0, C0, 0, 0, 0);
      C0 = __builtin_amdgcn_mfma_f32_16x16x32_f16(A[0][1], B1, C0, 0, 0, 0);
      C0 = __builtin_amdgcn_mfma_f32_16x16x32_f16(A[0][2], B2, C0, 0, 0, 0);
      C1 = __builtin_amdgcn_mfma_f32_16x16x32_f16(A[1][0], B0, C1, 0, 0, 0);
      C1 = __builtin_amdgcn_mfma_f32_16x16x32_f16(A[1][1], B1, C1, 0, 0, 0);
      C1 = __builtin_amdgcn_mfma_f32_16x16x32_f16(A[1][2], B2, C1, 0, 0, 0);
      C2 = __builtin_amdgcn_mfma_f32_16x16x32_f16(A[2][0], B0, C2, 0, 0, 0);
      C2 = __builtin_amdgcn_mfma_f32_16x16x32_f16(A[2][1], B1, C2, 0, 0, 0);
      C2 = __builtin_amdgcn_mfma_f32_16x16x32_f16(A[2][2], B2, C2, 0, 0, 0);
#pragma unroll
      for (int mt = 0; mt < 3; ++mt) {
        const f32x4 C = (mt == 0) ? C0 : (mt == 1) ? C1 : C2;
        const float cc = sigm(C[1]) * c[mt][nt] + sigm(C[0]) * tanh_f(C[2]);
        c[mt][nt] = cc;
        const float hv = sigm(C[3]) * tanh_f(cc);
        const unsigned short hbb = __builtin_bit_cast(unsigned short, (_Float16)hv);
        if (nt & 1) hp[mt][nt >> 1] |= ((unsigned int)hbb << 16);
        else        hp[mt][nt >> 1]  = (unsigned int)hbb;
      }
    }
    if (st < 4) {
      // writes go to hb[1-p]: its readers finished before the barrier that
      // ended step st-1 -> no pre-write barrier needed.
      const int wb = ((1 - p) * 2 + dir) * 64;
#pragma unroll
      for (int mt = 0; mt < 3; ++mt)
#pragma unroll
        for (int nt = 0; nt < 4; ++nt)
          hb[(wb + nt * 16 + col) * 72 + 16 + ug * 12 + mt * 4 + grp] =
              (unsigned short)(hp[mt][nt >> 1] >> (16 * (nt & 1)));
      // refresh next step's x[32..47] slice (4 u16 global loads)
      const int sp = dir ? (3 - st) : (st + 1);
      unsigned short xv[4];
#pragma unroll
      for (int i = 0; i < 4; ++i)
        xv[i] = xth[(size_t)(sp * 48 + 32 + ug * 4 + i) * NB + b0 + lane];
      unsigned int* xc = (unsigned int*)hb + (wb + lane) * 36 + ug * 2;
      xc[0] = pku2(xv[0], xv[1]);
      xc[1] = pku2(xv[2], xv[3]);
      __syncthreads();                     // ONE barrier per step
    } else {
      __syncthreads();                     // all xs/hb reads done
#pragma unroll
      for (int mt = 0; mt < 3; ++mt)
#pragma unroll
        for (int nt = 0; nt < 4; ++nt)
          hf[(nt * 16 + col) * 100 + dir * 48 + ug * 12 + mt * 4 + grp] =
              (float)__builtin_bit_cast(_Float16,
                  (unsigned short)(hp[mt][nt >> 1] >> (16 * (nt & 1))));
      __syncthreads();
    }
  }

  // ---- MLP head (structure = r13/r14; e1o aliases hb, e2o aliases hf) ----
  {
    float acc[6];
#pragma unroll
    for (int r = 0; r < 6; ++r) acc[r] = e1b[w * 6 + r];
#pragma unroll
    for (int q = 0; q < 24; ++q) {
      const float4 v = *reinterpret_cast<const float4*>(&hf[lane * 100 + q * 4]);
#pragma unroll
      for (int r = 0; r < 6; ++r) {
        const int rr = w * 6 + r;
        acc[r] = __builtin_fmaf(e1w[rr * 96 + q * 4 + 0], v.x, acc[r]);
        acc[r] = __builtin_fmaf(e1w[rr * 96 + q * 4 + 1], v.y, acc[r]);
        acc[r] = __builtin_fmaf(e1w[rr * 96 + q * 4 + 2], v.z, acc[r]);
        acc[r] = __builtin_fmaf(e1w[rr * 96 + q * 4 + 3], v.w, acc[r]);
      }
    }
    __syncthreads();
    unsigned int* ep = (unsigned int*)&e1o[lane * 54];
#pragma unroll
    for (int u = 0; u < 3; ++u) {
      const float a0 = acc[2*u]   > 0.0f ? acc[2*u]   : 0.0f;
      const float a1 = acc[2*u+1] > 0.0f ? acc[2*u+1] : 0.0f;
      ep[w * 3 + u] = pkh2(a0, a1);
    }
  }
  __syncthreads();

  {
    const int e2base = (w < 4) ? w * 5 : 20 + (w - 4) * 4;
    const int e2cnt  = (w < 4) ? 5 : 4;
    float acc[5];
#pragma unroll
    for (int r = 0; r < 5; ++r) acc[r] = (r < e2cnt) ? e2b[e2base + r] : 0.0f;
    const unsigned int* eq = (const unsigned int*)&e1o[lane * 54];
#pragma unroll
    for (int q = 0; q < 24; ++q) {
      const unsigned int u = eq[q];
      const float v0 = loh(u), v1 = hih(u);
#pragma unroll
      for (int r = 0; r < 5; ++r) {
        if (r < e2cnt) {
          const int rr = e2base + r;
          acc[r] = __builtin_fmaf(e2w[rr * 48 + 2*q],     v0, acc[r]);
          acc[r] = __builtin_fmaf(e2w[rr * 48 + 2*q + 1], v1, acc[r]);
        }
      }
    }
    __syncthreads();                      // all hf/e1 reads done before e2o write
#pragma unroll
    for (int r = 0; r < 5; ++r)
      if (r < e2cnt) e2o[lane * 44 + e2base + r] = acc[r] > 0.0f ? acc[r] : 0.0f;
  }
  __syncthreads();

  if (w < 6) {
    float a = e3b[w];
#pragma unroll
    for (int q = 0; q < 9; ++q) {
      const float4 v = *reinterpret_cast<const float4*>(&e2o[lane * 44 + q * 4]);
      a = __builtin_fmaf(e3w[w * 36 + q * 4 + 0], v.x, a);
      a = __builtin_fmaf(e3w[w * 36 + q * 4 + 1], v.y, a);
      a = __builtin_fmaf(e3w[w * 36 + q * 4 + 2], v.z, a);
      a = __builtin_fmaf(e3w[w * 36 + q * 4 + 3], v.w, a);
    }
    out[(size_t)(b0 + lane) * 6 + w] = a;
  }
}

extern "C" void kernel_launch(void* const* d_in, const int* in_sizes, int n_in,
                              void* d_out, int out_size, void* d_ws, size_t ws_size,
                              hipStream_t stream)
{
  const float* nf    = (const float*)d_in[0];
  const float* pos   = (const float*)d_in[1];
  const float* att   = (const float*)d_in[2];
  const float* msg_w = (const float*)d_in[3];
  const float* msg_b = (const float*)d_in[4];
  const float* gw_ih = (const float*)d_in[5];
  const float* gw_hh = (const float*)d_in[6];
  const float* gb_ih = (const float*)d_in[7];
  const float* gb_hh = (const float*)d_in[8];
  const float* wi_fw = (const float*)d_in[9];
  const float* wh_fw = (const float*)d_in[10];
  const float* bi_fw = (const float*)d_in[11];
  const float* bh_fw = (const float*)d_in[12];
  const float* wi_bw = (const float*)d_in[13];
  const float* wh_bw = (const float*)d_in[14];
  const float* bi_bw = (const float*)d_in[15];
  const float* bh_bw = (const float*)d_in[16];
  const float* e1w   = (const float*)d_in[17];
  const float* e1b   = (const float*)d_in[18];
  const float* e2w   = (const float*)d_in[19];
  const float* e2b   = (const float*)d_in[20];
  const float* e3w   = (const float*)d_in[21];
  const float* e3b   = (const float*)d_in[22];

  unsigned short* xth   = (unsigned short*)d_ws;
  unsigned short* wfrag = xth + (size_t)SL * 48 * NB;
  float*          bsum  = (float*)(wfrag + 36864);
  unsigned short* mfrag = (unsigned short*)(bsum + 384);
  float*          mbias = (float*)(mfrag + 2048);
  float*          outp  = (float*)d_out;

  prep_kernel<<<154, 256, 0, stream>>>(
      wi_fw, wh_fw, bi_fw, bh_fw, wi_bw, wh_bw, bi_bw, bh_bw,
      msg_w, msg_b, gw_ih, gw_hh, gb_ih, gb_hh,
      wfrag, bsum, mfrag, mbias);

  msg_mfma_kernel<<<(NB * SL) / 64, 256, 0, stream>>>(
      nf, pos, att, mfrag, mbias, xth);

  lstm_mfma_kernel<<<NB / 64, 512, 0, stream>>>(
      xth, wfrag, bsum, e1w, e1b, e2w, e2b, e3w, e3b, outp);
}

// Round 17
// 126.989 us; speedup vs baseline: 1.0689x; 1.0689x over previous
//
#include <hip/hip_runtime.h>
#include <cstddef>

#define NB 65536
#define SL 5

typedef _Float16 f16;
typedef f16 half8 __attribute__((ext_vector_type(8)));
typedef float f32x4 __attribute__((ext_vector_type(4)));

// Fast 1-ulp reciprocal (v_rcp_f32) instead of IEEE divide microcode.
__device__ __forceinline__ float sigm(float x) {
  return __builtin_amdgcn_rcpf(1.0f + __expf(-x));
}
__device__ __forceinline__ float tanh_f(float x) {
  return __builtin_fmaf(2.0f, __builtin_amdgcn_rcpf(1.0f + __expf(-2.0f * x)), -1.0f);
}
__device__ __forceinline__ unsigned int pkh2(float a, float b) {
  return (unsigned int)__builtin_bit_cast(unsigned short, (_Float16)a)
       | ((unsigned int)__builtin_bit_cast(unsigned short, (_Float16)b) << 16);
}
__device__ __forceinline__ float loh(unsigned int u) {
  return (float)__builtin_bit_cast(_Float16, (unsigned short)(u & 0xffffu));
}
__device__ __forceinline__ float hih(unsigned int u) {
  return (float)__builtin_bit_cast(_Float16, (unsigned short)(u >> 16));
}

// ---------------------------------------------------------------------------
// prep: f16 MFMA A-fragments.
// ---------------------------------------------------------------------------
__global__ __launch_bounds__(256) void prep_kernel(
    const float* __restrict__ wi_fw, const float* __restrict__ wh_fw,
    const float* __restrict__ bi_fw, const float* __restrict__ bh_fw,
    const float* __restrict__ wi_bw, const float* __restrict__ wh_bw,
    const float* __restrict__ bi_bw, const float* __restrict__ bh_bw,
    const float* __restrict__ msg_w, const float* __restrict__ msg_b,
    const float* __restrict__ gw_ih, const float* __restrict__ gw_hh,
    const float* __restrict__ gb_ih, const float* __restrict__ gb_hh,
    unsigned short* __restrict__ wfrag, float* __restrict__ bsum,
    unsigned short* __restrict__ mfrag, float* __restrict__ mbias)
{
  const int t = blockIdx.x * 256 + threadIdx.x;
  if (t < 36864) {
    const int i = t & 7, lane = (t >> 3) & 63, fid = t >> 9;
    const int kc = fid % 3, mt = (fid / 3) % 3, ug = (fid / 9) & 3, dir = fid / 36;
    const int k = kc * 32 + (lane >> 4) * 8 + i;
    const int r16 = lane & 15;
    const int j = ug * 12 + mt * 4 + (r16 >> 2);
    const int g = r16 & 3;
    const float* wi = dir ? wi_bw : wi_fw;
    const float* wh = dir ? wh_bw : wh_fw;
    const float v = (k < 48) ? wi[(g * 48 + j) * 48 + k] : wh[(g * 48 + j) * 48 + (k - 48)];
    wfrag[t] = __builtin_bit_cast(unsigned short, (_Float16)v);
  } else if (t < 37248) {
    const int q = t - 36864;
    const int r16 = q & 15, mt = (q >> 4) % 3, ug = (q / 48) & 3, dir = q / 192;
    const int j = ug * 12 + mt * 4 + (r16 >> 2);
    const int g = r16 & 3;
    const int row = g * 48 + j;
    bsum[q] = dir ? (bi_bw[row] + bh_bw[row]) : (bi_fw[row] + bh_fw[row]);
  } else if (t < 39296) {
    const int q = t - 37248;
    const int i = q & 7, lane = (q >> 3) & 63, fid = q >> 9;
    const int k = ((lane >> 4) << 3) + i;
    const int r16 = lane & 15;
    float v = 0.0f;
    if (fid == 0) {
      if (r16 < 12 && k >= 12 && k < 24) v = msg_w[r16 * 12 + (k - 12)];
    } else {
      const int R = (fid - 1) * 16 + r16;
      const int kind = R / 12, j = R % 12;
      if (kind == 0)      v = (k < 12) ? gw_ih[j * 12 + k]          : ((k < 24) ? gw_hh[j * 12 + (k - 12)] : 0.0f);
      else if (kind == 1) v = (k < 12) ? gw_ih[(12 + j) * 12 + k]   : ((k < 24) ? gw_hh[(12 + j) * 12 + (k - 12)] : 0.0f);
      else if (kind == 2) v = (k < 12) ? gw_ih[(24 + j) * 12 + k]   : 0.0f;
      else                v = (k >= 12 && k < 24) ? gw_hh[(24 + j) * 12 + (k - 12)] : 0.0f;
    }
    mfrag[q] = __builtin_bit_cast(unsigned short, (_Float16)v);
  } else if (t < 39360) {
    const int q = t - 39296;
    if (q < 16) mbias[q] = (q < 12) ? msg_b[q] : 0.0f;
    else {
      const int R = q - 16, kind = R / 12, j = R % 12;
      float v;
      if (kind == 0)      v = gb_ih[j] + gb_hh[j];
      else if (kind == 1) v = gb_ih[12 + j] + gb_hh[12 + j];
      else if (kind == 2) v = gb_ih[24 + j];
      else                v = gb_hh[24 + j];
      mbias[q] = v;
    }
  }
}

// ---------------------------------------------------------------------------
// Phase A via MFMA: sample-major xbuf epilogue (r10-verified, conflict-free).
// ---------------------------------------------------------------------------
__global__ __launch_bounds__(256) void msg_mfma_kernel(
    const float* __restrict__ nf, const float* __restrict__ pos,
    const float* __restrict__ att,
    const unsigned short* __restrict__ mfrag, const float* __restrict__ mbias,
    unsigned short* __restrict__ xth)
{
  __shared__ unsigned short B_lds[256][40];   // f16 bits, 80B rows
  __shared__ unsigned short g_lds[256][50];   // f16 bits, 100B rows
  unsigned short* xbuf = &g_lds[0][0];        // [64][50] alias (final pass only)

  const int tid  = threadIdx.x;
  const int lane = tid & 63;
  const int w    = __builtin_amdgcn_readfirstlane(tid >> 6);
  const int c16  = lane & 15;
  const int grp  = lane >> 4;
  const int own  = tid;
  const int node = own & 3;
  const int sl   = (own >> 6) * 16 + ((own >> 4) & 3) * 4 + ((own >> 2) & 3);

  half8 A1 = *reinterpret_cast<const half8*>(mfrag + (size_t)lane * 8);
  half8 A2[3];
#pragma unroll
  for (int mt = 0; mt < 3; ++mt)
    A2[mt] = *reinterpret_cast<const half8*>(mfrag + (size_t)((1 + mt) * 64 + lane) * 8);
  const f32x4 bias1 = *reinterpret_cast<const f32x4*>(mbias + grp * 4);
  f32x4 bias2[3];
#pragma unroll
  for (int mt = 0; mt < 3; ++mt)
    bias2[mt] = *reinterpret_cast<const f32x4*>(mbias + 16 + mt * 16 + grp * 4);

  {
    unsigned int* bz = reinterpret_cast<unsigned int*>(&B_lds[0][0]);
#pragma unroll
    for (int q = 0; q < 6; ++q)  bz[tid * 20 + q] = 0u;
#pragma unroll
    for (int q = 12; q < 16; ++q) bz[tid * 20 + q] = 0u;
  }

  const int sid = blockIdx.x * 64 + sl;
  const int s   = sid >> 16;
  const int b   = sid & (NB - 1);
  float h[12];
  {
    const size_t ib = ((size_t)(b * SL + s) * 4 + node) * 6;
    const float2* n2 = (const float2*)(nf  + ib);
    const float2* p2 = (const float2*)(pos + ib);
#pragma unroll
    for (int q = 0; q < 3; q++) {
      float2 v = n2[q]; h[q*2]   = v.x; h[q*2+1]   = v.y;
      float2 u = p2[q]; h[6+q*2] = u.x; h[6+q*2+1] = u.y;
    }
  }
  float ta[4];
  {
    float4 v = *(const float4*)(att + ((size_t)(b * SL + s) * 4 + node) * 4);
    ta[0] = v.x; ta[1] = v.y; ta[2] = v.z; ta[3] = v.w;
  }
  {
    unsigned int* bp = (unsigned int*)&B_lds[own][0];
#pragma unroll
    for (int d = 0; d < 6; ++d) bp[6 + d] = pkh2(h[2*d], h[2*d+1]);
  }
  __syncthreads();

#pragma unroll 1
  for (int pass = 0; pass < 2; ++pass) {
    // --- GEMM1: m_all (rows 0..11) ---
#pragma unroll
    for (int nt = 0; nt < 4; ++nt) {
      const int col = w * 64 + nt * 16 + c16;
      half8 B = *reinterpret_cast<const half8*>(&B_lds[col][grp * 8]);
      f32x4 C = __builtin_amdgcn_mfma_f32_16x16x32_f16(A1, B, bias1, 0, 0, 0);
      if (grp < 3) {
        unsigned int* gp = (unsigned int*)&g_lds[col][0];
        gp[grp * 2]     = pkh2(C[0], C[1]);
        gp[grp * 2 + 1] = pkh2(C[2], C[3]);
      }
    }
    __syncthreads();

    // --- attention mix (paired u32 reads; quad-broadcast) ---
    {
      const int cb = own & ~3;
      float mv[12];
#pragma unroll
      for (int d = 0; d < 12; ++d) mv[d] = 0.0f;
#pragma unroll
      for (int ww = 0; ww < 4; ++ww) {
        const float a = ta[ww];
        const unsigned int* gp = (const unsigned int*)&g_lds[cb + ww][0];
#pragma unroll
        for (int dq = 0; dq < 6; ++dq) {
          const unsigned int u = gp[dq];
          mv[2*dq]   = __builtin_fmaf(a, loh(u), mv[2*dq]);
          mv[2*dq+1] = __builtin_fmaf(a, hih(u), mv[2*dq+1]);
        }
      }
      unsigned int* bp = (unsigned int*)&B_lds[own][0];
#pragma unroll
      for (int d = 0; d < 6; ++d) bp[d] = pkh2(mv[2*d], mv[2*d+1]);
    }
    __syncthreads();

    // --- GEMM2: gates, 48 rows = [r | z | n_ih | n_hh] ---
#pragma unroll
    for (int nt = 0; nt < 4; ++nt) {
      const int col = w * 64 + nt * 16 + c16;
      half8 B = *reinterpret_cast<const half8*>(&B_lds[col][grp * 8]);
      f32x4 C0 = __builtin_amdgcn_mfma_f32_16x16x32_f16(A2[0], B, bias2[0], 0, 0, 0);
      f32x4 C1 = __builtin_amdgcn_mfma_f32_16x16x32_f16(A2[1], B, bias2[1], 0, 0, 0);
      f32x4 C2 = __builtin_amdgcn_mfma_f32_16x16x32_f16(A2[2], B, bias2[2], 0, 0, 0);
      unsigned int* gp = (unsigned int*)&g_lds[col][0];
      gp[grp * 2]      = pkh2(C0[0], C0[1]);
      gp[grp * 2 + 1]  = pkh2(C0[2], C0[3]);
      gp[8 + grp * 2]     = pkh2(C1[0], C1[1]);
      gp[8 + grp * 2 + 1] = pkh2(C1[2], C1[3]);
      gp[16 + grp * 2]     = pkh2(C2[0], C2[1]);
      gp[16 + grp * 2 + 1] = pkh2(C2[2], C2[3]);
    }
    __syncthreads();

    // --- GRU update (gate reads hoisted; pass 1 writes to xbuf) ---
    {
      unsigned int ur[6], uz[6], ui[6], uh[6];
      const unsigned int* gq = (const unsigned int*)&g_lds[own][0];
#pragma unroll
      for (int jq = 0; jq < 6; ++jq) {
        ur[jq] = gq[jq];
        uz[jq] = gq[6 + jq];
        ui[jq] = gq[12 + jq];
        uh[jq] = gq[18 + jq];
      }
      if (pass) __syncthreads();   // xbuf aliases g_lds: all gate reads done
#pragma unroll
      for (int jq = 0; jq < 6; ++jq) {
        {
          const float r = sigm(loh(ur[jq])), z = sigm(loh(uz[jq]));
          const float g = tanh_f(loh(ui[jq]) + r * loh(uh[jq]));
          h[2*jq] = (1.0f - z) * g + z * h[2*jq];
        }
        {
          const float r = sigm(hih(ur[jq])), z = sigm(hih(uz[jq]));
          const float g = tanh_f(hih(ui[jq]) + r * hih(uh[jq]));
          h[2*jq+1] = (1.0f - z) * g + z * h[2*jq+1];
        }
      }
      if (pass == 0) {
        unsigned int* bp = (unsigned int*)&B_lds[own][0];
#pragma unroll
        for (int d = 0; d < 6; ++d) bp[6 + d] = pkh2(h[2*d], h[2*d+1]);
      } else {
#pragma unroll
        for (int d = 0; d < 12; ++d)
          xbuf[sl * 50 + d * 4 + node] =
              __builtin_bit_cast(unsigned short, (_Float16)h[d]);
      }
    }
    __syncthreads();
  }

  // --- store: lane i = batch b0+i reads xbuf[i*50+f] (conflict-free) ---
  const int b0   = (blockIdx.x * 64) & (NB - 1);
  const int sblk = blockIdx.x >> 10;           // block-uniform s
#pragma unroll
  for (int ff = 0; ff < 12; ++ff) {
    const int f = w * 12 + ff;
    xth[(size_t)(sblk * 48 + f) * NB + b0 + lane] = xbuf[lane * 50 + f];
  }
}

// ---------------------------------------------------------------------------
// Phase B+C: biLSTM via MFMA + MLP head — exact r10 configuration (empirical
// optimum: 71.4us). f32 bias/hvf, write-phase x loads, 39936B LDS, hf f32
// batch-major for the float4 MLP, e1o f16 odd-stride. All post-r10 edits
// (T14 early loads, launch-bounds clamps, packing shaves, barrier
// restructures) measured neutral-to-catastrophic; reverted.
// ---------------------------------------------------------------------------
__global__ __launch_bounds__(512) void lstm_mfma_kernel(
    const unsigned short* __restrict__ xth,
    const unsigned short* __restrict__ wfrag,
    const float* __restrict__ bsum,
    const float* __restrict__ e1w, const float* __restrict__ e1b,
    const float* __restrict__ e2w, const float* __restrict__ e2b,
    const float* __restrict__ e3w, const float* __restrict__ e3b,
    float* __restrict__ out)
{
  __shared__ float4 pool4[2496];               // 39936 B
  float* pool = (float*)pool4;
  unsigned short* act = (unsigned short*)pool; // [2][64][104] halfs (26624 B)
  float* hf  = pool;                           // [64][100] f32 (aliases act; after loop)
  float* e1o = pool + 6656;                    // [64][52] f32
  float* e2o = pool;                           // [64][44] f32 (aliases hf; after e1)

  const int tid  = threadIdx.x;
  const int lane = tid & 63;
  const int w    = __builtin_amdgcn_readfirstlane(tid >> 6);
  const int dir  = w & 1;
  const int ug   = w >> 1;
  const int b0   = blockIdx.x * 64;
  const int col  = lane & 15;
  const int grp  = lane >> 4;

  half8 A[3][3];
#pragma unroll
  for (int mt = 0; mt < 3; ++mt)
#pragma unroll
    for (int kc = 0; kc < 3; ++kc) {
      const int fid = ((dir * 4 + ug) * 3 + mt) * 3 + kc;
      A[mt][kc] = *reinterpret_cast<const half8*>(wfrag + (size_t)(fid * 64 + lane) * 8);
    }
  f32x4 bias[3];
#pragma unroll
  for (int mt = 0; mt < 3; ++mt)
    bias[mt] = *reinterpret_cast<const f32x4*>(bsum + ((dir * 4 + ug) * 3 + mt) * 16 + grp * 4);

#pragma unroll
  for (int ff = 0; ff < 6; ++ff) {
    const int f = w * 6 + ff;
    act[(0 * 64 + lane) * 104 + f] = xth[(size_t)(0 * 48 + f) * NB + b0 + lane];
    act[(1 * 64 + lane) * 104 + f] = xth[(size_t)(4 * 48 + f) * NB + b0 + lane];
  }
#pragma unroll
  for (int jj = 0; jj < 12; ++jj)
    act[(dir * 64 + lane) * 104 + 48 + ug * 12 + jj] = 0;
  __syncthreads();

  float c[3][4];
#pragma unroll
  for (int mt = 0; mt < 3; ++mt)
#pragma unroll
    for (int nt = 0; nt < 4; ++nt) c[mt][nt] = 0.0f;

#pragma unroll 1
  for (int st = 0; st < 5; ++st) {
    float hvf[3][4];
#pragma unroll
    for (int nt = 0; nt < 4; ++nt) {
      const int n = nt * 16 + col;
      const unsigned short* ar = &act[(dir * 64 + n) * 104];
      half8 B0 = *reinterpret_cast<const half8*>(ar + grp * 8);
      half8 B1 = *reinterpret_cast<const half8*>(ar + 32 + grp * 8);
      half8 B2 = *reinterpret_cast<const half8*>(ar + 64 + grp * 8);
      f32x4 C0 = bias[0], C1 = bias[1], C2 = bias[2];
      C0 = __builtin_amdgcn_mfma_f32_16x16x32_f16(A[0][0], B0, C0, 0, 0, 0);
      C0 = __builtin_amdgcn_mfma_f32_16x16x32_f16(A[0][1], B1, C0, 0, 0, 0);
      C0 = __builtin_amdgcn_mfma_f32_16x16x32_f16(A[0][2], B2, C0, 0, 0, 0);
      C1 = __builtin_amdgcn_mfma_f32_16x16x32_f16(A[1][0], B0, C1, 0, 0, 0);
      C1 = __builtin_amdgcn_mfma_f32_16x16x32_f16(A[1][1], B1, C1, 0, 0, 0);
      C1 = __builtin_amdgcn_mfma_f32_16x16x32_f16(A[1][2], B2, C1, 0, 0, 0);
      C2 = __builtin_amdgcn_mfma_f32_16x16x32_f16(A[2][0], B0, C2, 0, 0, 0);
      C2 = __builtin_amdgcn_mfma_f32_16x16x32_f16(A[2][1], B1, C2, 0, 0, 0);
      C2 = __builtin_amdgcn_mfma_f32_16x16x32_f16(A[2][2], B2, C2, 0, 0, 0);
#pragma unroll
      for (int mt = 0; mt < 3; ++mt) {
        const f32x4 C = (mt == 0) ? C0 : (mt == 1) ? C1 : C2;
        const float cc = sigm(C[1]) * c[mt][nt] + sigm(C[0]) * tanh_f(C[2]);
        c[mt][nt] = cc;
        hvf[mt][nt] = sigm(C[3]) * tanh_f(cc);
      }
    }
    __syncthreads();                       // all act reads complete
    if (st < 4) {
#pragma unroll
      for (int mt = 0; mt < 3; ++mt)
#pragma unroll
        for (int nt = 0; nt < 4; ++nt)
          act[(dir * 64 + nt * 16 + col) * 104 + 48 + ug * 12 + mt * 4 + grp] =
              __builtin_bit_cast(unsigned short, (_Float16)hvf[mt][nt]);
      const int s0 = st + 1, s1 = 3 - st;
#pragma unroll
      for (int ff = 0; ff < 6; ++ff) {
        const int f = w * 6 + ff;
        act[(0 * 64 + lane) * 104 + f] = xth[(size_t)(s0 * 48 + f) * NB + b0 + lane];
        act[(1 * 64 + lane) * 104 + f] = xth[(size_t)(s1 * 48 + f) * NB + b0 + lane];
      }
    } else {
      // final h -> f32 batch-major hf[64][100]
#pragma unroll
      for (int mt = 0; mt < 3; ++mt)
#pragma unroll
        for (int nt = 0; nt < 4; ++nt)
          hf[(nt * 16 + col) * 100 + dir * 48 + ug * 12 + mt * 4 + grp] = hvf[mt][nt];
    }
    __syncthreads();
  }

  // ---- MLP head: float4 activation reads, accumulators hoisted ----
  {
    float acc[6];
#pragma unroll
    for (int r = 0; r < 6; ++r) acc[r] = e1b[w * 6 + r];
#pragma unroll
    for (int q = 0; q < 24; ++q) {
      const float4 v = *reinterpret_cast<const float4*>(&hf[lane * 100 + q * 4]);
#pragma unroll
      for (int r = 0; r < 6; ++r) {
        const int rr = w * 6 + r;
        acc[r] = __builtin_fmaf(e1w[rr * 96 + q * 4 + 0], v.x, acc[r]);
        acc[r] = __builtin_fmaf(e1w[rr * 96 + q * 4 + 1], v.y, acc[r]);
        acc[r] = __builtin_fmaf(e1w[rr * 96 + q * 4 + 2], v.z, acc[r]);
        acc[r] = __builtin_fmaf(e1w[rr * 96 + q * 4 + 3], v.w, acc[r]);
      }
    }
    __syncthreads();
#pragma unroll
    for (int r = 0; r < 6; ++r)
      e1o[lane * 52 + w * 6 + r] = acc[r] > 0.0f ? acc[r] : 0.0f;
  }
  __syncthreads();

  {
    const int e2base = (w < 4) ? w * 5 : 20 + (w - 4) * 4;
    const int e2cnt  = (w < 4) ? 5 : 4;
    float acc[5];
#pragma unroll
    for (int r = 0; r < 5; ++r) acc[r] = (r < e2cnt) ? e2b[e2base + r] : 0.0f;
#pragma unroll
    for (int q = 0; q < 12; ++q) {
      const float4 v = *reinterpret_cast<const float4*>(&e1o[lane * 52 + q * 4]);
#pragma unroll
      for (int r = 0; r < 5; ++r) {
        if (r < e2cnt) {
          const int rr = e2base + r;
          acc[r] = __builtin_fmaf(e2w[rr * 48 + q * 4 + 0], v.x, acc[r]);
          acc[r] = __builtin_fmaf(e2w[rr * 48 + q * 4 + 1], v.y, acc[r]);
          acc[r] = __builtin_fmaf(e2w[rr * 48 + q * 4 + 2], v.z, acc[r]);
          acc[r] = __builtin_fmaf(e2w[rr * 48 + q * 4 + 3], v.w, acc[r]);
        }
      }
    }
    __syncthreads();
#pragma unroll
    for (int r = 0; r < 5; ++r)
      if (r < e2cnt) e2o[lane * 44 + e2base + r] = acc[r] > 0.0f ? acc[r] : 0.0f;
  }
  __syncthreads();

  if (w < 6) {
    float a = e3b[w];
#pragma unroll
    for (int q = 0; q < 9; ++q) {
      const float4 v = *reinterpret_cast<const float4*>(&e2o[lane * 44 + q * 4]);
      a = __builtin_fmaf(e3w[w * 36 + q * 4 + 0], v.x, a);
      a = __builtin_fmaf(e3w[w * 36 + q * 4 + 1], v.y, a);
      a = __builtin_fmaf(e3w[w * 36 + q * 4 + 2], v.z, a);
      a = __builtin_fmaf(e3w[w * 36 + q * 4 + 3], v.w, a);
    }
    out[(size_t)(b0 + lane) * 6 + w] = a;
  }
}

extern "C" void kernel_launch(void* const* d_in, const int* in_sizes, int n_in,
                              void* d_out, int out_size, void* d_ws, size_t ws_size,
                              hipStream_t stream)
{
  const float* nf    = (const float*)d_in[0];
  const float* pos   = (const float*)d_in[1];
  const float* att   = (const float*)d_in[2];
  const float* msg_w = (const float*)d_in[3];
  const float* msg_b = (const float*)d_in[4];
  const float* gw_ih = (const float*)d_in[5];
  const float* gw_hh = (const float*)d_in[6];
  const float* gb_ih = (const float*)d_in[7];
  const float* gb_hh = (const float*)d_in[8];
  const float* wi_fw = (const float*)d_in[9];
  const float* wh_fw = (const float*)d_in[10];
  const float* bi_fw = (const float*)d_in[11];
  const float* bh_fw = (const float*)d_in[12];
  const float* wi_bw = (const float*)d_in[13];
  const float* wh_bw = (const float*)d_in[14];
  const float* bi_bw = (const float*)d_in[15];
  const float* bh_bw = (const float*)d_in[16];
  const float* e1w   = (const float*)d_in[17];
  const float* e1b   = (const float*)d_in[18];
  const float* e2w   = (const float*)d_in[19];
  const float* e2b   = (const float*)d_in[20];
  const float* e3w   = (const float*)d_in[21];
  const float* e3b   = (const float*)d_in[22];

  unsigned short* xth   = (unsigned short*)d_ws;
  unsigned short* wfrag = xth + (size_t)SL * 48 * NB;
  float*          bsum  = (float*)(wfrag + 36864);
  unsigned short* mfrag = (unsigned short*)(bsum + 384);
  float*          mbias = (float*)(mfrag + 2048);
  float*          outp  = (float*)d_out;

  prep_kernel<<<154, 256, 0, stream>>>(
      wi_fw, wh_fw, bi_fw, bh_fw, wi_bw, wh_bw, bi_bw, bh_bw,
      msg_w, msg_b, gw_ih, gw_hh, gb_ih, gb_hh,
      wfrag, bsum, mfrag, mbias);

  msg_mfma_kernel<<<(NB * SL) / 64, 256, 0, stream>>>(
      nf, pos, att, mfrag, mbias, xth);

  lstm_mfma_kernel<<<NB / 64, 512, 0, stream>>>(
      xth, wfrag, bsum, e1w, e1b, e2w, e2b, e3w, e3b, outp);
}